// Round 9
// baseline (414.791 us; speedup 1.0000x reference)
//
#include <hip/hip_runtime.h>
#include <cfloat>
#include <stdint.h>

// Problem constants
#define NROWS   32768
#define NCODES  8192
#define KDIM    256
#define QOUT_OFFSET (NROWS * KDIM)

// Main-kernel tiling (champion structure, full-codebook scan)
#define BM      64              // rows per block
#define BN      256             // codes per block-tile (4 waves x 64)
#define NKC     (KDIM / 32)     // 8
#define NIT     (NCODES / BN * NKC)    // 32 ct * 8 kc = 256
#define THREADS 256             // 4 waves

// Fragment-order panel geometry (per 128-code panel), [pt][kc]-linear
#define BPAN 8192               // 128 codes * 32 k * 2 B, one split
#define BBUF (2 * BPAN)         // hi+lo 16384
#define PANEL_BYTES (8u * 1024 * 1024)
#define ALDS_SPLIT 32768        // 64 rows * 256 k * 2 B per split
// LDS: 2 * 32768 = 65536 B -> 2 blocks/CU

typedef __bf16 bf16x4 __attribute__((ext_vector_type(4)));
typedef __bf16 bf16x8 __attribute__((ext_vector_type(8)));
typedef float  f32x4  __attribute__((ext_vector_type(4)));

// ---------------------------------------------------------------------------
// K1: codebook -> hi/lo bf16 panels in MFMA-fragment order, + cnorm.
// R9: re-sharded for parallelism — 512 blocks x 256 threads (16 codes/block,
// 16 threads/row). Thread (row, sg) owns kc = sg>>1 and octs (sg&1)*2+{0,1}:
// 4 loads + 4 stores per thread (was 16+32 at 128 blocks). Store-base
// formula identical to the champion's -> byte-identical panel layout.
// ---------------------------------------------------------------------------
__global__ void vq_panel_kernel(const float* __restrict__ cb,
                                char* __restrict__ cbP,
                                float* __restrict__ cnorm) {
    const int t    = threadIdx.x;
    const int row  = t >> 4;             // 0..15
    const int sg   = t & 15;             // 0..15
    const int code = blockIdx.x * 16 + row;
    const int cl   = code & 127;
    const int pt   = code >> 7;
    const int kc   = sg >> 1;            // 0..7
    const int oct0 = (sg & 1) * 2;       // 0 or 2
    const float4* cb4 = (const float4*)cb;

    float ssq = 0.f;
    #pragma unroll
    for (int i2 = 0; i2 < 2; ++i2) {
        const int oct = oct0 + i2;
        const int f   = kc * 8 + oct * 2;        // float4 index, covers k..k+7
        float4 v0 = cb4[(size_t)code * 64 + f];
        float4 v1 = cb4[(size_t)code * 64 + f + 1];
        float xs[8] = {v0.x, v0.y, v0.z, v0.w, v1.x, v1.y, v1.z, v1.w};
        bf16x8 h, l;
        #pragma unroll
        for (int e = 0; e < 8; ++e) {
            __bf16 hh = (__bf16)xs[e];
            h[e] = hh;
            l[e] = (__bf16)(xs[e] - (float)hh);
            ssq  = fmaf(xs[e], xs[e], ssq);
        }
        const int lanefrag = (oct << 4) | (cl & 15);
        char* base = cbP + ((size_t)(pt * NKC + kc)) * BBUF
                         + ((cl >> 4) * 64 + lanefrag) * 16;
        *(bf16x8*)base          = h;
        *(bf16x8*)(base + BPAN) = l;
    }
    // reduce ssq across the 16 sg-lanes of this row
    ssq += __shfl_xor(ssq, 1, 64);
    ssq += __shfl_xor(ssq, 2, 64);
    ssq += __shfl_xor(ssq, 4, 64);
    ssq += __shfl_xor(ssq, 8, 64);
    if (sg == 0) cnorm[code] = ssq;
}

// ---------------------------------------------------------------------------
// K2: split-bf16 MFMA distances + FULL-codebook argmin per row.
// Champion hot loop (VGPR 128, no spill, MfmaUtil ~60%) byte-identical.
// FUSE=1 (panels in d_ws -> quant region unaliased): each block gathers its
// own 64 codebook rows into quant in the tail, eliminating K4 + one launch.
// ---------------------------------------------------------------------------
template <int FUSE>
__global__ __launch_bounds__(THREADS, 2) void vq_main_kernel(
        const float* __restrict__ z, const char* __restrict__ cbP,
        const float* __restrict__ cnorm, const float* __restrict__ cb,
        float* __restrict__ quant, float* __restrict__ idx_out) {

    __shared__ __align__(16) char Alds[2 * ALDS_SPLIT];   // 65536 B

    const int t     = threadIdx.x;
    const int wave  = t >> 6;
    const int lane  = t & 63;
    const int l15   = lane & 15;
    const int row0  = blockIdx.x * BM;
    const int wp    = wave >> 1;           // wave's panel sub-group
    const int bvoff = ((wave & 1) * 256 + lane) * 16;   // lane part of B addr

    const float4* z4 = (const float4*)z;

    f32x4 acc[4][4];
    float mv[16];
    int   mi[16];
    #pragma unroll
    for (int i = 0; i < 4; ++i)
        #pragma unroll
        for (int j = 0; j < 4; ++j)
            acc[i][j] = (f32x4){0.f, 0.f, 0.f, 0.f};
    #pragma unroll
    for (int s = 0; s < 16; ++s) { mv[s] = FLT_MAX; mi[s] = 0; }

    // ---- prologue: stage A (all 8 kc, hi+lo, fragment order) ----
    {
        const int arow = t >> 2;
        const int aseg = t & 3;
        #pragma unroll
        for (int p = 0; p < 8; ++p) {
            float4 f0 = z4[(size_t)(row0 + arow) * 64 + aseg * 16 + 2 * p];
            float4 f1 = z4[(size_t)(row0 + arow) * 64 + aseg * 16 + 2 * p + 1];
            float xs[8] = {f0.x, f0.y, f0.z, f0.w, f1.x, f1.y, f1.z, f1.w};
            bf16x8 hv, lv;
            #pragma unroll
            for (int e = 0; e < 8; ++e) {
                __bf16 hh = (__bf16)xs[e];
                hv[e] = hh;
                lv[e] = (__bf16)(xs[e] - (float)hh);
            }
            int kc  = aseg * 2 + (p >> 2);
            int oct = p & 3;
            int slot = ((kc * 4 + (arow >> 4)) * 64 + (oct << 4) + (arow & 15)) * 16;
            *(bf16x8*)(Alds + slot)              = hv;
            *(bf16x8*)(Alds + ALDS_SPLIT + slot) = lv;
        }
    }

    // ---- prologue: B fragments for iter 0 (ct=0, kc=0) ----
    bf16x8 B0h[4], B0l[4], B1h[4], B1l[4];
    {
        const char* pb  = cbP + ((size_t)wp * 8) * BBUF + bvoff;
        const char* pbl = pb + BPAN;
        #pragma unroll
        for (int j = 0; j < 4; ++j) {
            B0h[j] = *(const bf16x8*)(pb  + j * 1024);
            B0l[j] = *(const bf16x8*)(pbl + j * 1024);
        }
    }

    __syncthreads();   // A ready; the ONLY barrier before the reduction

    // ---- prologue: A fragments for iter 0 (kc=0) ----
    bf16x8 A0h[4], A0l[4], A1h[4], A1l[4];
    {
        const char* ab = Alds + (lane << 4);
        #pragma unroll
        for (int i = 0; i < 4; ++i) {
            A0h[i] = *(const bf16x8*)(ab + i * 1024);
            A0l[i] = *(const bf16x8*)(ab + ALDS_SPLIT + i * 1024);
        }
    }

    float cnj[4];

#define VQ_BODY(N, CAH, CAL, NAH, NAL, CBH, CBL, NBH, NBL)                    \
    {                                                                         \
        const int ct = (N) >> 3, kc = (N) & 7;                                \
        const int np = (N) + 1;                                               \
        if (np < NIT) {                                                       \
            const int ct1 = np >> 3, kc1 = np & 7;                            \
            const char* pb  = cbP                                             \
                + ((size_t)((ct1 * 2 + wp) * 8 + kc1)) * BBUF + bvoff;        \
            const char* pbl = pb + BPAN;                                      \
            _Pragma("unroll")                                                 \
            for (int j = 0; j < 4; ++j) {                                     \
                NBH[j] = *(const bf16x8*)(pb  + j * 1024);                    \
                NBL[j] = *(const bf16x8*)(pbl + j * 1024);                    \
            }                                                                 \
        }                                                                     \
        {                                                                     \
            const int kcn = np & 7;                                           \
            const char* ab = Alds + (kcn << 12) + (lane << 4);                \
            _Pragma("unroll")                                                 \
            for (int i = 0; i < 4; ++i) {                                     \
                NAH[i] = *(const bf16x8*)(ab + i * 1024);                     \
                NAL[i] = *(const bf16x8*)(ab + ALDS_SPLIT + i * 1024);        \
            }                                                                 \
        }                                                                     \
        if (kc == 0) {                                                        \
            _Pragma("unroll")                                                 \
            for (int j = 0; j < 4; ++j)                                       \
                cnj[j] = cnorm[(ct * 16 + wave * 4 + j) * 16 + l15];          \
        }                                                                     \
        __builtin_amdgcn_s_setprio(1);                                        \
        _Pragma("unroll")                                                     \
        for (int i = 0; i < 4; ++i)                                           \
            _Pragma("unroll")                                                 \
            for (int j = 0; j < 4; ++j)                                       \
                acc[i][j] = __builtin_amdgcn_mfma_f32_16x16x32_bf16(          \
                                CAH[i], CBH[j], acc[i][j], 0, 0, 0);          \
        _Pragma("unroll")                                                     \
        for (int i = 0; i < 4; ++i)                                           \
            _Pragma("unroll")                                                 \
            for (int j = 0; j < 4; ++j)                                       \
                acc[i][j] = __builtin_amdgcn_mfma_f32_16x16x32_bf16(          \
                                CAH[i], CBL[j], acc[i][j], 0, 0, 0);          \
        _Pragma("unroll")                                                     \
        for (int i = 0; i < 4; ++i)                                           \
            _Pragma("unroll")                                                 \
            for (int j = 0; j < 4; ++j)                                       \
                acc[i][j] = __builtin_amdgcn_mfma_f32_16x16x32_bf16(          \
                                CAL[i], CBH[j], acc[i][j], 0, 0, 0);          \
        __builtin_amdgcn_s_setprio(0);                                        \
        if (kc == 7) {                                                        \
            _Pragma("unroll")                                                 \
            for (int j = 0; j < 4; ++j) {                                     \
                int code = (ct * 16 + wave * 4 + j) * 16 + l15;               \
                float cn = cnj[j];                                            \
                _Pragma("unroll")                                             \
                for (int i = 0; i < 4; ++i) {                                 \
                    _Pragma("unroll")                                         \
                    for (int r = 0; r < 4; ++r) {                             \
                        float d = fmaf(-2.f, acc[i][j][r], cn);               \
                        int s = i * 4 + r;                                    \
                        if (d < mv[s]) { mv[s] = d; mi[s] = code; }           \
                    }                                                         \
                    acc[i][j] = (f32x4){0.f, 0.f, 0.f, 0.f};                  \
                }                                                             \
            }                                                                 \
        }                                                                     \
    }

    for (int n = 0; n < NIT; n += 2) {
        VQ_BODY(n,     A0h, A0l, A1h, A1l, B0h, B0l, B1h, B1l)
        VQ_BODY(n + 1, A1h, A1l, A0h, A0l, B1h, B1l, B0h, B0l)
    }
#undef VQ_BODY

    // ---- reduction: 16-lane butterfly (codes), then cross-wave via LDS ----
    #pragma unroll
    for (int s = 0; s < 16; ++s) {
        #pragma unroll
        for (int m = 1; m <= 8; m <<= 1) {
            float ov = __shfl_xor(mv[s], m, 64);
            int   oi = __shfl_xor(mi[s], m, 64);
            if (ov < mv[s] || (ov == mv[s] && oi < mi[s])) { mv[s] = ov; mi[s] = oi; }
        }
    }
    __syncthreads();
    float* redV  = (float*)Alds;                // [4 wave][64 rows]
    int*   redI  = (int*)(Alds + 4 * BM * 4);
    int*   bestI = (int*)(Alds + 8 * BM * 4);   // final per-row winner
    if (l15 == 0) {
        int qq = lane >> 4;
        #pragma unroll
        for (int i = 0; i < 4; ++i)
            #pragma unroll
            for (int r = 0; r < 4; ++r) {
                int ml = i * 16 + qq * 4 + r;
                redV[wave * BM + ml] = mv[i * 4 + r];
                redI[wave * BM + ml] = mi[i * 4 + r];
            }
    }
    __syncthreads();
    if (t < BM) {
        float bv = redV[t];
        int   bi = redI[t];
        #pragma unroll
        for (int w = 1; w < 4; ++w) {
            float v  = redV[w * BM + t];
            int   id = redI[w * BM + t];
            if (v < bv || (v == bv && id < bi)) { bv = v; bi = id; }
        }
        idx_out[row0 + t] = (float)bi;
        if (FUSE) bestI[t] = bi;
    }

    if (FUSE) {
        // ---- fused gather: block writes its own 64 quant rows ----
        __syncthreads();
        const int grow = t >> 2;
        const int gseg = t & 3;
        const int best = bestI[grow];
        const float4* src = (const float4*)cb + (size_t)best * (KDIM / 4);
        float4* dst = (float4*)quant + (size_t)(row0 + grow) * (KDIM / 4);
        #pragma unroll
        for (int i = 0; i < 16; ++i)
            dst[gseg * 16 + i] = src[gseg * 16 + i];
    }
}

// ---------------------------------------------------------------------------
// K4 (fallback only, panels in d_out): gather codebook rows into quantized
// output after K2 completes.
// ---------------------------------------------------------------------------
__global__ void vq_gather_kernel(const float* __restrict__ cb,
                                 const float* __restrict__ idx_f,
                                 float* __restrict__ quant) {
    const int t   = threadIdx.x;
    const int row = blockIdx.x * 64 + (t >> 2);
    const int seg = t & 3;
    const int best = (int)idx_f[row];
    const float4* src = (const float4*)cb + (size_t)best * (KDIM / 4);
    float4* dst = (float4*)quant + (size_t)row * (KDIM / 4);
    #pragma unroll
    for (int i = 0; i < 16; ++i)
        dst[seg * 16 + i] = src[seg * 16 + i];
}

// ---------------------------------------------------------------------------
extern "C" void kernel_launch(void* const* d_in, const int* in_sizes, int n_in,
                              void* d_out, int out_size, void* d_ws, size_t ws_size,
                              hipStream_t stream) {
    const float* z  = (const float*)d_in[0];
    const float* cb = (const float*)d_in[1];
    float* quant   = (float*)d_out;
    float* idx_out = (float*)d_out + QOUT_OFFSET;
    float* cnorm   = (float*)d_ws;                 // 32 KB scratch

    const bool fuse = ws_size >= (size_t)(32 * 1024) + PANEL_BYTES;
    char* cbP = fuse ? ((char*)d_ws + 32 * 1024)   // panels in workspace
                     : (char*)d_out;               // fallback: quant region

    vq_panel_kernel<<<NCODES / 16, 256, 0, stream>>>(cb, cbP, cnorm);
    if (fuse) {
        vq_main_kernel<1><<<NROWS / BM, THREADS, 0, stream>>>(
            z, cbP, cnorm, cb, quant, idx_out);
    } else {
        vq_main_kernel<0><<<NROWS / BM, THREADS, 0, stream>>>(
            z, cbP, cnorm, cb, quant, idx_out);
        vq_gather_kernel<<<NROWS / 64, 256, 0, stream>>>(cb, idx_out, quant);
    }
}

// Round 10
// 405.049 us; speedup vs baseline: 1.0241x; 1.0241x over previous
//
#include <hip/hip_runtime.h>
#include <cfloat>
#include <stdint.h>

// Problem constants
#define NROWS   32768
#define NCODES  8192
#define KDIM    256
#define QOUT_OFFSET (NROWS * KDIM)

// Main-kernel tiling (champion structure, full-codebook scan)
#define BM      64              // rows per block
#define BN      256             // codes per block-tile (4 waves x 64)
#define NKC     (KDIM / 32)     // 8
#define NIT     (NCODES / BN * NKC)    // 32 ct * 8 kc = 256
#define THREADS 256             // 4 waves

// Fragment-order panel geometry (per 128-code panel), [pt][kc]-linear
#define BPAN 8192               // 128 codes * 32 k * 2 B, one split
#define BBUF (2 * BPAN)         // hi+lo 16384
#define PANEL_BYTES (8u * 1024 * 1024)
#define ALDS_SPLIT 32768        // 64 rows * 256 k * 2 B per split
// LDS: 2 * 32768 = 65536 B -> 2 blocks/CU

typedef __bf16 bf16x4 __attribute__((ext_vector_type(4)));
typedef __bf16 bf16x8 __attribute__((ext_vector_type(8)));
typedef float  f32x4  __attribute__((ext_vector_type(4)));

// ---------------------------------------------------------------------------
// K1: codebook -> hi/lo bf16 panels in MFMA-fragment order, + cnorm.
// R10: staged transpose through LDS. R9's null result showed K1 is
// store-COALESCING-bound, not parallelism-bound: fragment-order global
// stores scatter a wave's 64 lanes across 16KB-apart panels. Now:
//   phase 1: coalesced global reads (128-B runs) -> bf16 hi/lo -> LDS
//            image in fragment order (scatter hits LDS, not HBM)
//   phase 2: linear LDS reads -> fully-coalesced 1KB/wave global stores
// Byte layout produced is identical to the champion's:
//   LDS off = ((kc*2+jjl)*64 + (fl>>1)*16 + c15)*16 + (fl&1)*8
//   global  = panel(pt,kc) + chunk*2048 + (off & 2047)  [hi; lo at +BPAN]
// ---------------------------------------------------------------------------
__global__ __launch_bounds__(256) void vq_panel_kernel(
        const float* __restrict__ cb, char* __restrict__ cbP,
        float* __restrict__ cnorm) {
    __shared__ __align__(16) char P[32768];     // hi 16KB | lo 16KB

    const int t     = threadIdx.x;
    const int b     = blockIdx.x;               // 256 blocks
    const int pt    = b >> 2;                   // 128-code panel group
    const int chunk = b & 3;                    // 32-row chunk (jj pair)
    const int code0 = pt * 128 + chunk * 32;
    const int r     = t >> 3;                   // 0..31 local row
    const int c15   = r & 15;
    const int jjl   = r >> 4;                   // 0/1
    const int fl    = t & 7;                    // float4 sub-index

    // ---- phase 1: coalesced read, convert, LDS scatter ----
    const float4* src = (const float4*)cb + (size_t)(code0 + r) * 64;
    float ssq = 0.f;
    #pragma unroll
    for (int i = 0; i < 8; ++i) {               // i == kc
        float4 v = src[i * 8 + fl];             // lanes: consecutive float4
        float xs[4] = {v.x, v.y, v.z, v.w};
        bf16x4 h, l;
        #pragma unroll
        for (int e = 0; e < 4; ++e) {
            __bf16 hh = (__bf16)xs[e];
            h[e] = hh;
            l[e] = (__bf16)(xs[e] - (float)hh);
            ssq  = fmaf(xs[e], xs[e], ssq);
        }
        // f = i*8+fl -> kc=i, oct=fl>>1, rem=(fl&1)*4
        const int off = ((i * 2 + jjl) * 64 + ((fl >> 1) << 4) + c15) * 16
                      + (fl & 1) * 8;
        *(bf16x4*)(P + off)         = h;
        *(bf16x4*)(P + 16384 + off) = l;
    }
    // cnorm: reduce across the row's 8 (consecutive) lanes
    ssq += __shfl_xor(ssq, 1, 64);
    ssq += __shfl_xor(ssq, 2, 64);
    ssq += __shfl_xor(ssq, 4, 64);
    if (fl == 0) cnorm[code0 + r] = ssq;

    __syncthreads();

    // ---- phase 2: linear LDS read, fully-coalesced global store ----
    #pragma unroll
    for (int s = 0; s < 4; ++s) {
        const int L  = (s * 256 + t) * 16;      // 0..16383, 16B slots
        const int kc = L >> 11;                 // 2KB per kc region
        const int w  = L & 2047;
        char* g = cbP + ((size_t)(pt * NKC + kc)) * BBUF + chunk * 2048 + w;
        *(bf16x8*)g          = *(const bf16x8*)(P + L);
        *(bf16x8*)(g + BPAN) = *(const bf16x8*)(P + 16384 + L);
    }
}

// ---------------------------------------------------------------------------
// K2: split-bf16 MFMA distances + FULL-codebook argmin per row.
// Champion hot loop (VGPR 128, no spill, MfmaUtil ~60%) byte-identical.
// FUSE=1 (panels in d_ws -> quant region unaliased): each block gathers its
// own 64 codebook rows into quant in the tail, eliminating K4 + one launch.
// ---------------------------------------------------------------------------
template <int FUSE>
__global__ __launch_bounds__(THREADS, 2) void vq_main_kernel(
        const float* __restrict__ z, const char* __restrict__ cbP,
        const float* __restrict__ cnorm, const float* __restrict__ cb,
        float* __restrict__ quant, float* __restrict__ idx_out) {

    __shared__ __align__(16) char Alds[2 * ALDS_SPLIT];   // 65536 B

    const int t     = threadIdx.x;
    const int wave  = t >> 6;
    const int lane  = t & 63;
    const int l15   = lane & 15;
    const int row0  = blockIdx.x * BM;
    const int wp    = wave >> 1;           // wave's panel sub-group
    const int bvoff = ((wave & 1) * 256 + lane) * 16;   // lane part of B addr

    const float4* z4 = (const float4*)z;

    f32x4 acc[4][4];
    float mv[16];
    int   mi[16];
    #pragma unroll
    for (int i = 0; i < 4; ++i)
        #pragma unroll
        for (int j = 0; j < 4; ++j)
            acc[i][j] = (f32x4){0.f, 0.f, 0.f, 0.f};
    #pragma unroll
    for (int s = 0; s < 16; ++s) { mv[s] = FLT_MAX; mi[s] = 0; }

    // ---- prologue: stage A (all 8 kc, hi+lo, fragment order) ----
    {
        const int arow = t >> 2;
        const int aseg = t & 3;
        #pragma unroll
        for (int p = 0; p < 8; ++p) {
            float4 f0 = z4[(size_t)(row0 + arow) * 64 + aseg * 16 + 2 * p];
            float4 f1 = z4[(size_t)(row0 + arow) * 64 + aseg * 16 + 2 * p + 1];
            float xs[8] = {f0.x, f0.y, f0.z, f0.w, f1.x, f1.y, f1.z, f1.w};
            bf16x8 hv, lv;
            #pragma unroll
            for (int e = 0; e < 8; ++e) {
                __bf16 hh = (__bf16)xs[e];
                hv[e] = hh;
                lv[e] = (__bf16)(xs[e] - (float)hh);
            }
            int kc  = aseg * 2 + (p >> 2);
            int oct = p & 3;
            int slot = ((kc * 4 + (arow >> 4)) * 64 + (oct << 4) + (arow & 15)) * 16;
            *(bf16x8*)(Alds + slot)              = hv;
            *(bf16x8*)(Alds + ALDS_SPLIT + slot) = lv;
        }
    }

    // ---- prologue: B fragments for iter 0 (ct=0, kc=0) ----
    bf16x8 B0h[4], B0l[4], B1h[4], B1l[4];
    {
        const char* pb  = cbP + ((size_t)wp * 8) * BBUF + bvoff;
        const char* pbl = pb + BPAN;
        #pragma unroll
        for (int j = 0; j < 4; ++j) {
            B0h[j] = *(const bf16x8*)(pb  + j * 1024);
            B0l[j] = *(const bf16x8*)(pbl + j * 1024);
        }
    }

    __syncthreads();   // A ready; the ONLY barrier before the reduction

    // ---- prologue: A fragments for iter 0 (kc=0) ----
    bf16x8 A0h[4], A0l[4], A1h[4], A1l[4];
    {
        const char* ab = Alds + (lane << 4);
        #pragma unroll
        for (int i = 0; i < 4; ++i) {
            A0h[i] = *(const bf16x8*)(ab + i * 1024);
            A0l[i] = *(const bf16x8*)(ab + ALDS_SPLIT + i * 1024);
        }
    }

    float cnj[4];

#define VQ_BODY(N, CAH, CAL, NAH, NAL, CBH, CBL, NBH, NBL)                    \
    {                                                                         \
        const int ct = (N) >> 3, kc = (N) & 7;                                \
        const int np = (N) + 1;                                               \
        if (np < NIT) {                                                       \
            const int ct1 = np >> 3, kc1 = np & 7;                            \
            const char* pb  = cbP                                             \
                + ((size_t)((ct1 * 2 + wp) * 8 + kc1)) * BBUF + bvoff;        \
            const char* pbl = pb + BPAN;                                      \
            _Pragma("unroll")                                                 \
            for (int j = 0; j < 4; ++j) {                                     \
                NBH[j] = *(const bf16x8*)(pb  + j * 1024);                    \
                NBL[j] = *(const bf16x8*)(pbl + j * 1024);                    \
            }                                                                 \
        }                                                                     \
        {                                                                     \
            const int kcn = np & 7;                                           \
            const char* ab = Alds + (kcn << 12) + (lane << 4);                \
            _Pragma("unroll")                                                 \
            for (int i = 0; i < 4; ++i) {                                     \
                NAH[i] = *(const bf16x8*)(ab + i * 1024);                     \
                NAL[i] = *(const bf16x8*)(ab + ALDS_SPLIT + i * 1024);        \
            }                                                                 \
        }                                                                     \
        if (kc == 0) {                                                        \
            _Pragma("unroll")                                                 \
            for (int j = 0; j < 4; ++j)                                       \
                cnj[j] = cnorm[(ct * 16 + wave * 4 + j) * 16 + l15];          \
        }                                                                     \
        __builtin_amdgcn_s_setprio(1);                                        \
        _Pragma("unroll")                                                     \
        for (int i = 0; i < 4; ++i)                                           \
            _Pragma("unroll")                                                 \
            for (int j = 0; j < 4; ++j)                                       \
                acc[i][j] = __builtin_amdgcn_mfma_f32_16x16x32_bf16(          \
                                CAH[i], CBH[j], acc[i][j], 0, 0, 0);          \
        _Pragma("unroll")                                                     \
        for (int i = 0; i < 4; ++i)                                           \
            _Pragma("unroll")                                                 \
            for (int j = 0; j < 4; ++j)                                       \
                acc[i][j] = __builtin_amdgcn_mfma_f32_16x16x32_bf16(          \
                                CAH[i], CBL[j], acc[i][j], 0, 0, 0);          \
        _Pragma("unroll")                                                     \
        for (int i = 0; i < 4; ++i)                                           \
            _Pragma("unroll")                                                 \
            for (int j = 0; j < 4; ++j)                                       \
                acc[i][j] = __builtin_amdgcn_mfma_f32_16x16x32_bf16(          \
                                CAL[i], CBH[j], acc[i][j], 0, 0, 0);          \
        __builtin_amdgcn_s_setprio(0);                                        \
        if (kc == 7) {                                                        \
            _Pragma("unroll")                                                 \
            for (int j = 0; j < 4; ++j) {                                     \
                int code = (ct * 16 + wave * 4 + j) * 16 + l15;               \
                float cn = cnj[j];                                            \
                _Pragma("unroll")                                             \
                for (int i = 0; i < 4; ++i) {                                 \
                    _Pragma("unroll")                                         \
                    for (int r = 0; r < 4; ++r) {                             \
                        float d = fmaf(-2.f, acc[i][j][r], cn);               \
                        int s = i * 4 + r;                                    \
                        if (d < mv[s]) { mv[s] = d; mi[s] = code; }           \
                    }                                                         \
                    acc[i][j] = (f32x4){0.f, 0.f, 0.f, 0.f};                  \
                }                                                             \
            }                                                                 \
        }                                                                     \
    }

    for (int n = 0; n < NIT; n += 2) {
        VQ_BODY(n,     A0h, A0l, A1h, A1l, B0h, B0l, B1h, B1l)
        VQ_BODY(n + 1, A1h, A1l, A0h, A0l, B1h, B1l, B0h, B0l)
    }
#undef VQ_BODY

    // ---- reduction: 16-lane butterfly (codes), then cross-wave via LDS ----
    #pragma unroll
    for (int s = 0; s < 16; ++s) {
        #pragma unroll
        for (int m = 1; m <= 8; m <<= 1) {
            float ov = __shfl_xor(mv[s], m, 64);
            int   oi = __shfl_xor(mi[s], m, 64);
            if (ov < mv[s] || (ov == mv[s] && oi < mi[s])) { mv[s] = ov; mi[s] = oi; }
        }
    }
    __syncthreads();
    float* redV  = (float*)Alds;                // [4 wave][64 rows]
    int*   redI  = (int*)(Alds + 4 * BM * 4);
    int*   bestI = (int*)(Alds + 8 * BM * 4);   // final per-row winner
    if (l15 == 0) {
        int qq = lane >> 4;
        #pragma unroll
        for (int i = 0; i < 4; ++i)
            #pragma unroll
            for (int r = 0; r < 4; ++r) {
                int ml = i * 16 + qq * 4 + r;
                redV[wave * BM + ml] = mv[i * 4 + r];
                redI[wave * BM + ml] = mi[i * 4 + r];
            }
    }
    __syncthreads();
    if (t < BM) {
        float bv = redV[t];
        int   bi = redI[t];
        #pragma unroll
        for (int w = 1; w < 4; ++w) {
            float v  = redV[w * BM + t];
            int   id = redI[w * BM + t];
            if (v < bv || (v == bv && id < bi)) { bv = v; bi = id; }
        }
        idx_out[row0 + t] = (float)bi;
        if (FUSE) bestI[t] = bi;
    }

    if (FUSE) {
        // ---- fused gather: block writes its own 64 quant rows ----
        __syncthreads();
        const int grow = t >> 2;
        const int gseg = t & 3;
        const int best = bestI[grow];
        const float4* src = (const float4*)cb + (size_t)best * (KDIM / 4);
        float4* dst = (float4*)quant + (size_t)(row0 + grow) * (KDIM / 4);
        #pragma unroll
        for (int i = 0; i < 16; ++i)
            dst[gseg * 16 + i] = src[gseg * 16 + i];
    }
}

// ---------------------------------------------------------------------------
// K4 (fallback only, panels in d_out): gather codebook rows into quantized
// output after K2 completes.
// ---------------------------------------------------------------------------
__global__ void vq_gather_kernel(const float* __restrict__ cb,
                                 const float* __restrict__ idx_f,
                                 float* __restrict__ quant) {
    const int t   = threadIdx.x;
    const int row = blockIdx.x * 64 + (t >> 2);
    const int seg = t & 3;
    const int best = (int)idx_f[row];
    const float4* src = (const float4*)cb + (size_t)best * (KDIM / 4);
    float4* dst = (float4*)quant + (size_t)row * (KDIM / 4);
    #pragma unroll
    for (int i = 0; i < 16; ++i)
        dst[seg * 16 + i] = src[seg * 16 + i];
}

// ---------------------------------------------------------------------------
extern "C" void kernel_launch(void* const* d_in, const int* in_sizes, int n_in,
                              void* d_out, int out_size, void* d_ws, size_t ws_size,
                              hipStream_t stream) {
    const float* z  = (const float*)d_in[0];
    const float* cb = (const float*)d_in[1];
    float* quant   = (float*)d_out;
    float* idx_out = (float*)d_out + QOUT_OFFSET;
    float* cnorm   = (float*)d_ws;                 // 32 KB scratch

    const bool fuse = ws_size >= (size_t)(32 * 1024) + PANEL_BYTES;
    char* cbP = fuse ? ((char*)d_ws + 32 * 1024)   // panels in workspace
                     : (char*)d_out;               // fallback: quant region

    vq_panel_kernel<<<256, 256, 0, stream>>>(cb, cbP, cnorm);
    if (fuse) {
        vq_main_kernel<1><<<NROWS / BM, THREADS, 0, stream>>>(
            z, cbP, cnorm, cb, quant, idx_out);
    } else {
        vq_main_kernel<0><<<NROWS / BM, THREADS, 0, stream>>>(
            z, cbP, cnorm, cb, quant, idx_out);
        vq_gather_kernel<<<NROWS / 64, 256, 0, stream>>>(cb, idx_out, quant);
    }
}

// Round 11
// 385.122 us; speedup vs baseline: 1.0770x; 1.0517x over previous
//
#include <hip/hip_runtime.h>
#include <cfloat>
#include <stdint.h>

// Problem constants
#define NROWS   32768
#define NCODES  8192
#define KDIM    256
#define QOUT_OFFSET (NROWS * KDIM)

// Main-kernel tiling (champion structure, full-codebook scan)
#define BM      64              // rows per block
#define BN      256             // codes per block-tile (4 waves x 64)
#define NKC     (KDIM / 32)     // 8
#define NCT     (NCODES / BN)   // 32 ct iterations
#define THREADS 256             // 4 waves

// Fragment-order panel geometry (per 128-code panel), [pt][kc]-linear
#define BPAN 8192               // 128 codes * 32 k * 2 B, one split
#define BBUF (2 * BPAN)         // hi+lo 16384
#define PANEL_BYTES (8u * 1024 * 1024)
#define ALDS_SPLIT 32768        // 64 rows * 256 k * 2 B per split
// LDS: 2 * 32768 = 65536 B -> 2 blocks/CU

typedef __bf16 bf16x4 __attribute__((ext_vector_type(4)));
typedef __bf16 bf16x8 __attribute__((ext_vector_type(8)));
typedef float  f32x4  __attribute__((ext_vector_type(4)));

// ---------------------------------------------------------------------------
// K1: codebook -> hi/lo bf16 panels via staged LDS transpose (R10), + cnorm.
// Coalesced reads -> fragment-order LDS image -> coalesced 1KB/wave stores.
// ---------------------------------------------------------------------------
__global__ __launch_bounds__(256) void vq_panel_kernel(
        const float* __restrict__ cb, char* __restrict__ cbP,
        float* __restrict__ cnorm) {
    __shared__ __align__(16) char P[32768];     // hi 16KB | lo 16KB

    const int t     = threadIdx.x;
    const int b     = blockIdx.x;               // 256 blocks
    const int pt    = b >> 2;                   // 128-code panel group
    const int chunk = b & 3;                    // 32-row chunk (jj pair)
    const int code0 = pt * 128 + chunk * 32;
    const int r     = t >> 3;                   // 0..31 local row
    const int c15   = r & 15;
    const int jjl   = r >> 4;                   // 0/1
    const int fl    = t & 7;                    // float4 sub-index

    // ---- phase 1: coalesced read, convert, LDS scatter ----
    const float4* src = (const float4*)cb + (size_t)(code0 + r) * 64;
    float ssq = 0.f;
    #pragma unroll
    for (int i = 0; i < 8; ++i) {               // i == kc
        float4 v = src[i * 8 + fl];
        float xs[4] = {v.x, v.y, v.z, v.w};
        bf16x4 h, l;
        #pragma unroll
        for (int e = 0; e < 4; ++e) {
            __bf16 hh = (__bf16)xs[e];
            h[e] = hh;
            l[e] = (__bf16)(xs[e] - (float)hh);
            ssq  = fmaf(xs[e], xs[e], ssq);
        }
        const int off = ((i * 2 + jjl) * 64 + ((fl >> 1) << 4) + c15) * 16
                      + (fl & 1) * 8;
        *(bf16x4*)(P + off)         = h;
        *(bf16x4*)(P + 16384 + off) = l;
    }
    ssq += __shfl_xor(ssq, 1, 64);
    ssq += __shfl_xor(ssq, 2, 64);
    ssq += __shfl_xor(ssq, 4, 64);
    if (fl == 0) cnorm[code0 + r] = ssq;

    __syncthreads();

    // ---- phase 2: linear LDS read, fully-coalesced global store ----
    #pragma unroll
    for (int s = 0; s < 4; ++s) {
        const int L  = (s * 256 + t) * 16;      // 0..16383, 16B slots
        const int kc = L >> 11;                 // 2KB per kc region
        const int w  = L & 2047;
        char* g = cbP + ((size_t)(pt * NKC + kc)) * BBUF + chunk * 2048 + w;
        *(bf16x8*)g          = *(const bf16x8*)(P + L);
        *(bf16x8*)(g + BPAN) = *(const bf16x8*)(P + 16384 + L);
    }
}

// ---------------------------------------------------------------------------
// K2: split-bf16 MFMA distances + FULL-codebook argmin per row.
// R11: ct-outer loop with 8 fully-unrolled kc bodies (KC is a compile-time
// literal): B pointer walks linearly (+BBUF, +9*BBUF at the kc6 slot), A
// ds_reads are immediates off one base, kc==0/7 branches dissolve into the
// unroll. Buffers/tile/occupancy identical to the champion (the proven
// no-spill point: VGPR 128 @ (256,2)).
// FUSE=1: panels in d_ws -> per-block gather tail replaces K4.
// ---------------------------------------------------------------------------
template <int FUSE>
__global__ __launch_bounds__(THREADS, 2) void vq_main_kernel(
        const float* __restrict__ z, const char* __restrict__ cbP,
        const float* __restrict__ cnorm, const float* __restrict__ cb,
        float* __restrict__ quant, float* __restrict__ idx_out) {

    __shared__ __align__(16) char Alds[2 * ALDS_SPLIT];   // 65536 B

    const int t     = threadIdx.x;
    const int wave  = t >> 6;
    const int lane  = t & 63;
    const int l15   = lane & 15;
    const int row0  = blockIdx.x * BM;
    const int wp    = wave >> 1;           // wave's panel sub-group
    const int bvoff = ((wave & 1) * 256 + lane) * 16;   // lane part of B addr

    const float4* z4 = (const float4*)z;

    f32x4 acc[4][4];
    float mv[16];
    int   mi[16];
    #pragma unroll
    for (int i = 0; i < 4; ++i)
        #pragma unroll
        for (int j = 0; j < 4; ++j)
            acc[i][j] = (f32x4){0.f, 0.f, 0.f, 0.f};
    #pragma unroll
    for (int s = 0; s < 16; ++s) { mv[s] = FLT_MAX; mi[s] = 0; }

    // ---- prologue: stage A (all 8 kc, hi+lo, fragment order) ----
    {
        const int arow = t >> 2;
        const int aseg = t & 3;
        #pragma unroll
        for (int p = 0; p < 8; ++p) {
            float4 f0 = z4[(size_t)(row0 + arow) * 64 + aseg * 16 + 2 * p];
            float4 f1 = z4[(size_t)(row0 + arow) * 64 + aseg * 16 + 2 * p + 1];
            float xs[8] = {f0.x, f0.y, f0.z, f0.w, f1.x, f1.y, f1.z, f1.w};
            bf16x8 hv, lv;
            #pragma unroll
            for (int e = 0; e < 8; ++e) {
                __bf16 hh = (__bf16)xs[e];
                hv[e] = hh;
                lv[e] = (__bf16)(xs[e] - (float)hh);
            }
            int kc  = aseg * 2 + (p >> 2);
            int oct = p & 3;
            int slot = ((kc * 4 + (arow >> 4)) * 64 + (oct << 4) + (arow & 15)) * 16;
            *(bf16x8*)(Alds + slot)              = hv;
            *(bf16x8*)(Alds + ALDS_SPLIT + slot) = lv;
        }
    }

    // ---- prologue: B fragments for (ct=0, kc=0) ----
    bf16x8 B0h[4], B0l[4], B1h[4], B1l[4];
    {
        const char* pb  = cbP + ((size_t)wp * 8) * BBUF + bvoff;
        const char* pbl0 = pb + BPAN;
        #pragma unroll
        for (int j = 0; j < 4; ++j) {
            B0h[j] = *(const bf16x8*)(pb   + j * 1024);
            B0l[j] = *(const bf16x8*)(pbl0 + j * 1024);
        }
    }
    // pbh/pbl always point at the NEXT panel to prefetch: (ct=0, kc=1)
    const char* pbh = cbP + ((size_t)(wp * 8 + 1)) * BBUF + bvoff;
    const char* pbl = pbh + BPAN;

    __syncthreads();   // A ready; the ONLY barrier before the reduction

    // ---- prologue: A fragments for kc=0 ----
    const char* ab = (const char*)Alds + (lane << 4);
    bf16x8 A0h[4], A0l[4], A1h[4], A1l[4];
    #pragma unroll
    for (int i = 0; i < 4; ++i) {
        A0h[i] = *(const bf16x8*)(ab + i * 1024);
        A0l[i] = *(const bf16x8*)(ab + ALDS_SPLIT + i * 1024);
    }

    float cnj[4];

// One kc body. KC is a LITERAL. Prefetch next B panel (linear walk) and
// next A fragments (immediates), then 48 MFMAs, epilogue only at KC==7.
#define VQ_KC(KC, INC, PRED, CAH, CAL, NAH, NAL, CBH, CBL, NBH, NBL)          \
    {                                                                         \
        if (PRED) {                                                           \
            _Pragma("unroll")                                                 \
            for (int j = 0; j < 4; ++j) {                                     \
                NBH[j] = *(const bf16x8*)(pbh + j * 1024);                    \
                NBL[j] = *(const bf16x8*)(pbl + j * 1024);                    \
            }                                                                 \
        }                                                                     \
        pbh += (INC); pbl += (INC);                                           \
        {                                                                     \
            constexpr int kcn = ((KC) + 1) & 7;                               \
            _Pragma("unroll")                                                 \
            for (int i = 0; i < 4; ++i) {                                     \
                NAH[i] = *(const bf16x8*)(ab + kcn * 4096 + i * 1024);        \
                NAL[i] = *(const bf16x8*)(ab + ALDS_SPLIT + kcn * 4096 + i * 1024); \
            }                                                                 \
        }                                                                     \
        __builtin_amdgcn_s_setprio(1);                                        \
        _Pragma("unroll")                                                     \
        for (int i = 0; i < 4; ++i)                                           \
            _Pragma("unroll")                                                 \
            for (int j = 0; j < 4; ++j)                                       \
                acc[i][j] = __builtin_amdgcn_mfma_f32_16x16x32_bf16(          \
                                CAH[i], CBH[j], acc[i][j], 0, 0, 0);          \
        _Pragma("unroll")                                                     \
        for (int i = 0; i < 4; ++i)                                           \
            _Pragma("unroll")                                                 \
            for (int j = 0; j < 4; ++j)                                       \
                acc[i][j] = __builtin_amdgcn_mfma_f32_16x16x32_bf16(          \
                                CAH[i], CBL[j], acc[i][j], 0, 0, 0);          \
        _Pragma("unroll")                                                     \
        for (int i = 0; i < 4; ++i)                                           \
            _Pragma("unroll")                                                 \
            for (int j = 0; j < 4; ++j)                                       \
                acc[i][j] = __builtin_amdgcn_mfma_f32_16x16x32_bf16(          \
                                CAL[i], CBH[j], acc[i][j], 0, 0, 0);          \
        __builtin_amdgcn_s_setprio(0);                                        \
        if ((KC) == 7) {                                                      \
            _Pragma("unroll")                                                 \
            for (int j = 0; j < 4; ++j) {                                     \
                const int  code = cb0 + j * 16;                               \
                const float cn  = cnj[j];                                     \
                _Pragma("unroll")                                             \
                for (int i = 0; i < 4; ++i) {                                 \
                    _Pragma("unroll")                                         \
                    for (int r = 0; r < 4; ++r) {                             \
                        float d = fmaf(-2.f, acc[i][j][r], cn);               \
                        int s = i * 4 + r;                                    \
                        if (d < mv[s]) { mv[s] = d; mi[s] = code; }           \
                    }                                                         \
                    acc[i][j] = (f32x4){0.f, 0.f, 0.f, 0.f};                  \
                }                                                             \
            }                                                                 \
        }                                                                     \
    }

    for (int ct = 0; ct < NCT; ++ct) {
        const int cb0 = (ct * 16 + wave * 4) * 16 + l15;
        #pragma unroll
        for (int j = 0; j < 4; ++j)
            cnj[j] = cnorm[cb0 + j * 16];        // used at KC==7: hidden

        VQ_KC(0, BBUF,     true,      A0h, A0l, A1h, A1l, B0h, B0l, B1h, B1l)
        VQ_KC(1, BBUF,     true,      A1h, A1l, A0h, A0l, B1h, B1l, B0h, B0l)
        VQ_KC(2, BBUF,     true,      A0h, A0l, A1h, A1l, B0h, B0l, B1h, B1l)
        VQ_KC(3, BBUF,     true,      A1h, A1l, A0h, A0l, B1h, B1l, B0h, B0l)
        VQ_KC(4, BBUF,     true,      A0h, A0l, A1h, A1l, B0h, B0l, B1h, B1l)
        VQ_KC(5, BBUF,     true,      A1h, A1l, A0h, A0l, B1h, B1l, B0h, B0l)
        VQ_KC(6, 9 * BBUF, true,      A0h, A0l, A1h, A1l, B0h, B0l, B1h, B1l)
        VQ_KC(7, BBUF,     ct < NCT - 1, A1h, A1l, A0h, A0l, B1h, B1l, B0h, B0l)
    }
#undef VQ_KC

    // ---- reduction: 16-lane butterfly (codes), then cross-wave via LDS ----
    #pragma unroll
    for (int s = 0; s < 16; ++s) {
        #pragma unroll
        for (int m = 1; m <= 8; m <<= 1) {
            float ov = __shfl_xor(mv[s], m, 64);
            int   oi = __shfl_xor(mi[s], m, 64);
            if (ov < mv[s] || (ov == mv[s] && oi < mi[s])) { mv[s] = ov; mi[s] = oi; }
        }
    }
    __syncthreads();
    float* redV  = (float*)Alds;                // [4 wave][64 rows]
    int*   redI  = (int*)(Alds + 4 * BM * 4);
    int*   bestI = (int*)(Alds + 8 * BM * 4);   // final per-row winner
    if (l15 == 0) {
        int qq = lane >> 4;
        #pragma unroll
        for (int i = 0; i < 4; ++i)
            #pragma unroll
            for (int r = 0; r < 4; ++r) {
                int ml = i * 16 + qq * 4 + r;
                redV[wave * BM + ml] = mv[i * 4 + r];
                redI[wave * BM + ml] = mi[i * 4 + r];
            }
    }
    __syncthreads();
    if (t < BM) {
        float bv = redV[t];
        int   bi = redI[t];
        #pragma unroll
        for (int w = 1; w < 4; ++w) {
            float v  = redV[w * BM + t];
            int   id = redI[w * BM + t];
            if (v < bv || (v == bv && id < bi)) { bv = v; bi = id; }
        }
        idx_out[row0 + t] = (float)bi;
        if (FUSE) bestI[t] = bi;
    }

    if (FUSE) {
        // ---- fused gather: block writes its own 64 quant rows ----
        __syncthreads();
        const int grow = t >> 2;
        const int gseg = t & 3;
        const int best = bestI[grow];
        const float4* src = (const float4*)cb + (size_t)best * (KDIM / 4);
        float4* dst = (float4*)quant + (size_t)(row0 + grow) * (KDIM / 4);
        #pragma unroll
        for (int i = 0; i < 16; ++i)
            dst[gseg * 16 + i] = src[gseg * 16 + i];
    }
}

// ---------------------------------------------------------------------------
// K4 (fallback only, panels in d_out): gather codebook rows into quantized
// output after K2 completes.
// ---------------------------------------------------------------------------
__global__ void vq_gather_kernel(const float* __restrict__ cb,
                                 const float* __restrict__ idx_f,
                                 float* __restrict__ quant) {
    const int t   = threadIdx.x;
    const int row = blockIdx.x * 64 + (t >> 2);
    const int seg = t & 3;
    const int best = (int)idx_f[row];
    const float4* src = (const float4*)cb + (size_t)best * (KDIM / 4);
    float4* dst = (float4*)quant + (size_t)row * (KDIM / 4);
    #pragma unroll
    for (int i = 0; i < 16; ++i)
        dst[seg * 16 + i] = src[seg * 16 + i];
}

// ---------------------------------------------------------------------------
extern "C" void kernel_launch(void* const* d_in, const int* in_sizes, int n_in,
                              void* d_out, int out_size, void* d_ws, size_t ws_size,
                              hipStream_t stream) {
    const float* z  = (const float*)d_in[0];
    const float* cb = (const float*)d_in[1];
    float* quant   = (float*)d_out;
    float* idx_out = (float*)d_out + QOUT_OFFSET;
    float* cnorm   = (float*)d_ws;                 // 32 KB scratch

    const bool fuse = ws_size >= (size_t)(32 * 1024) + PANEL_BYTES;
    char* cbP = fuse ? ((char*)d_ws + 32 * 1024)   // panels in workspace
                     : (char*)d_out;               // fallback: quant region

    vq_panel_kernel<<<256, 256, 0, stream>>>(cb, cbP, cnorm);
    if (fuse) {
        vq_main_kernel<1><<<NROWS / BM, THREADS, 0, stream>>>(
            z, cbP, cnorm, cb, quant, idx_out);
    } else {
        vq_main_kernel<0><<<NROWS / BM, THREADS, 0, stream>>>(
            z, cbP, cnorm, cb, quant, idx_out);
        vq_gather_kernel<<<NROWS / 64, 256, 0, stream>>>(cb, idx_out, quant);
    }
}